// Round 6
// baseline (499.410 us; speedup 1.0000x reference)
//
#include <hip/hip_runtime.h>

// Problem constants (B=2, C=512, H=128, W=256, G=8, maxdisp=48)
#define NB 2
#define NG 8
#define CG 64
#define HH 128
#define WW 256
#define ND 48
#define CHUNK 8            // channels staged per round (8 rounds)
#define TPB 128            // 2 waves; 32 w-tiles x 4 d-tiles
#define DT 12              // d per thread
#define WT 8               // w per thread
#define PADF 64            // 16 float4-slots of left pad (>= ND, 8-slot aligned)
#define ROWF (WW + PADF)   // 320 floats = 80 slots per stgt row

// XOR swizzle on float4-slot index (involution within aligned 8-slot blocks).
__device__ __forceinline__ int swz8(int q) { return q ^ ((q >> 3) & 7); }

__global__ __launch_bounds__(TPB, 3)
void gwc_kernel(const float* __restrict__ ref, const float* __restrict__ tgt,
                float* __restrict__ out) {
    __shared__ float sref[CHUNK][WW];    // 8 KB,  64 slots/row
    __shared__ float stgt[CHUNK][ROWF];  // 10 KB, 80 slots/row (slots 0..15 = pad)

    const int tid = threadIdx.x;
    const int wt  = tid & 31;            // w-tile: w in [8wt, 8wt+8)
    const int dt  = tid >> 5;            // d-tile 0..3: d in [12dt, 12dt+12)
    const int d0  = DT * dt;

    const int blk  = blockIdx.x;         // b*G*H + g*H + h
    const int hrow = blk % HH;
    const int bg   = blk / HH;

    // Zero the pad: physical floats [0,64) of each row (swz8 maps pad slots onto pad slots).
    for (int i = tid; i < CHUNK * PADF; i += TPB)
        stgt[i / PADF][i % PADF] = 0.0f;

    // Per-thread swizzled read offsets (floats; c enters via row index, const-folded).
    // rv: logical slots 2wt, 2wt+1 (stride-2 lane pattern -> conflict-free under swz8).
    const int r0 = 4 * swz8(2 * wt);
    const int r1 = 4 * swz8(2 * wt + 1);
    // tv: logical slots lo..lo+4, lo = 2wt + F, F = floor((53 - d0)/4) in {13,10,7,4}.
    const int F = (53 - d0) >> 2;
    int toff[5];
    #pragma unroll
    for (int k = 0; k < 5; ++k)
        toff[k] = 4 * swz8(2 * wt + F + k);   // logical slots in [4, 80)

    float acc[DT][WT];
    #pragma unroll
    for (int i = 0; i < DT; ++i)
        #pragma unroll
        for (int j = 0; j < WT; ++j) acc[i][j] = 0.0f;

    const size_t rowstride = (size_t)HH * WW;
    const float* refbase = ref + ((size_t)bg * CG * HH + hrow) * WW;
    const float* tgtbase = tgt + ((size_t)bg * CG * HH + hrow) * WW;

    for (int ch = 0; ch < CG / CHUNK; ++ch) {
        __syncthreads();  // previous chunk's reads done before overwrite
        // ---- stage CHUNK channels: coalesced global float4; 8-aligned swizzled LDS writes ----
        for (int i = tid; i < CHUNK * 64; i += TPB) {
            const int r = i >> 6;        // row in chunk
            const int q = i & 63;        // logical float4 slot
            const float* gr = refbase + (size_t)(ch * CHUNK + r) * rowstride + q * 4;
            const float* gt = tgtbase + (size_t)(ch * CHUNK + r) * rowstride + q * 4;
            *(float4*)&sref[r][4 * swz8(q)]      = *(const float4*)gr;       // aligned group
            *(float4*)&stgt[r][4 * swz8(q + 16)] = *(const float4*)gt;       // aligned group
        }
        __syncthreads();
        // ---- accumulate over this chunk's channels ----
        #pragma unroll
        for (int c = 0; c < CHUNK; ++c) {
            float rv[WT];
            *(float4*)&rv[0] = *(const float4*)&sref[c][r0];
            *(float4*)&rv[4] = *(const float4*)&sref[c][r1];
            // tv[p] = padded tgt float (2wt+F)*4 + p; needed float = 8wt+64+ww-d0-dd
            //       -> p = 12 + ww - dd, static in [1,19] for all dt.
            float tv[20];
            #pragma unroll
            for (int k = 0; k < 5; ++k)
                *(float4*)&tv[4 * k] = *(const float4*)&stgt[c][toff[k]];
            #pragma unroll
            for (int dd = 0; dd < DT; ++dd)
                #pragma unroll
                for (int ww = 0; ww < WT; ++ww)
                    acc[dd][ww] += rv[ww] * tv[12 + ww - dd];
        }
    }

    // ---- epilogue: out[((bg*ND + d)*HH + hrow)*WW + 8wt + {0,4}] ----
    // Half-wave split store shape (lanes 0-31 one d-tile, 32-63 another): r1/r3's
    // clean-WRITE_SIZE pattern.
    float* obase = out + ((size_t)bg * ND) * rowstride + (size_t)hrow * WW + 8 * wt;
    #pragma unroll
    for (int dd = 0; dd < DT; ++dd) {
        float* orow = obase + (size_t)(d0 + dd) * rowstride;
        *(float4*)&orow[0] = make_float4(acc[dd][0], acc[dd][1], acc[dd][2], acc[dd][3]);
        *(float4*)&orow[4] = make_float4(acc[dd][4], acc[dd][5], acc[dd][6], acc[dd][7]);
    }
}

extern "C" void kernel_launch(void* const* d_in, const int* in_sizes, int n_in,
                              void* d_out, int out_size, void* d_ws, size_t ws_size,
                              hipStream_t stream) {
    const float* ref = (const float*)d_in[0];
    const float* tgt = (const float*)d_in[1];
    float* out = (float*)d_out;
    const int grid = NB * NG * HH;   // 2048 blocks, one per (b, g, h)
    gwc_kernel<<<dim3(grid), dim3(TPB), 0, stream>>>(ref, tgt, out);
}

// Round 7
// 90.936 us; speedup vs baseline: 5.4919x; 5.4919x over previous
//
#include <hip/hip_runtime.h>

// Problem constants (B=2, C=512, H=128, W=256, G=8, maxdisp=48)
#define NB 2
#define NG 8
#define CG 64
#define HH 128
#define WW 256
#define ND 48
#define CHUNK 8            // channels staged per round (8 rounds)
#define TPB 256            // 4 waves; wave wv owns d in [12wv, 12wv+12)
#define DT 12              // d per thread
#define WT 4               // w per thread (w = 4*lane .. 4*lane+3)
#define PADF 64            // 16 float4-slots of left pad (>= ND, 8-slot aligned)
#define ROWF (WW + PADF)   // 320 floats = 80 slots per stgt row

// XOR swizzle on float4-slot index (involution within aligned 8-slot blocks;
// maps pad slots [0,16) onto pad slots, data slots onto data slots).
__device__ __forceinline__ int swz8(int q) { return q ^ ((q >> 3) & 7); }

__global__ __launch_bounds__(TPB, 4)
void gwc_kernel(const float* __restrict__ ref, const float* __restrict__ tgt,
                float* __restrict__ out) {
    __shared__ float sref[CHUNK][WW];    // 8 KB,  64 slots/row
    __shared__ float stgt[CHUNK][ROWF];  // 10 KB, 80 slots/row (slots 0..15 = pad)

    const int tid  = threadIdx.x;
    const int lane = tid & 63;
    const int wv   = tid >> 6;           // 0..3
    const int d0   = DT * wv;            // 0,12,24,36

    const int blk  = blockIdx.x;         // b*G*H + g*H + h
    const int hrow = blk % HH;
    const int bg   = blk / HH;

    // Zero the pad: physical floats [0,64) of each row.
    for (int i = tid; i < CHUNK * PADF; i += TPB)
        stgt[i / PADF][i % PADF] = 0.0f;

    // Per-thread swizzled read offsets (floats; c enters via row index, const-folded).
    const int roff = 4 * swz8(lane);     // rv: logical slot = lane (permutation)
    const int F = 13 - 3 * wv;           // tv base slot shift; extraction idx = 12+ww-dd
    int toff[4];
    #pragma unroll
    for (int k = 0; k < 4; ++k)
        toff[k] = 4 * swz8(lane + F + k);   // logical slots in [4, 80)

    float acc[DT][WT];
    #pragma unroll
    for (int i = 0; i < DT; ++i)
        #pragma unroll
        for (int j = 0; j < WT; ++j) acc[i][j] = 0.0f;

    const size_t rowstride = (size_t)HH * WW;
    const float* refbase = ref + ((size_t)bg * CG * HH + hrow) * WW;
    const float* tgtbase = tgt + ((size_t)bg * CG * HH + hrow) * WW;

    for (int ch = 0; ch < CG / CHUNK; ++ch) {
        __syncthreads();  // previous chunk's reads done before overwrite
        // ---- stage CHUNK channels: coalesced global float4; swizzled LDS writes ----
        // Thread tid handles (r=wv, q=lane) and (r=wv+4, q=lane): full slot
        // permutations per row -> conflict-free ds_write_b128.
        for (int i = tid; i < CHUNK * 64; i += TPB) {
            const int r = i >> 6;        // row in chunk
            const int q = i & 63;        // logical float4 slot
            const float* gr = refbase + (size_t)(ch * CHUNK + r) * rowstride + q * 4;
            const float* gt = tgtbase + (size_t)(ch * CHUNK + r) * rowstride + q * 4;
            *(float4*)&sref[r][4 * swz8(q)]      = *(const float4*)gr;
            *(float4*)&stgt[r][4 * swz8(q + 16)] = *(const float4*)gt;  // 8-aligned group
        }
        __syncthreads();
        // ---- accumulate over this chunk's channels ----
        #pragma unroll 2
        for (int c = 0; c < CHUNK; ++c) {
            float rv[WT];
            *(float4*)&rv[0] = *(const float4*)&sref[c][roff];
            // tv[4k+m] = padded tgt float 4*(lane+F+k)+m; needed float
            // 64 + 4*lane + ww - d0 - dd  ->  tv[12 + ww - dd], static in [1,15].
            float tv[16];
            #pragma unroll
            for (int k = 0; k < 4; ++k)
                *(float4*)&tv[4 * k] = *(const float4*)&stgt[c][toff[k]];
            #pragma unroll
            for (int dd = 0; dd < DT; ++dd)
                #pragma unroll
                for (int ww = 0; ww < WT; ++ww)
                    acc[dd][ww] += rv[ww] * tv[12 + ww - dd];
        }
    }

    // ---- epilogue: out[((bg*ND + d)*HH + hrow)*WW + 4*lane] ----
    // Whole wave writes one d-row per store: 64 x 16B = 1 KB contiguous.
    float* obase = out + ((size_t)bg * ND) * rowstride + (size_t)hrow * WW + 4 * lane;
    #pragma unroll
    for (int dd = 0; dd < DT; ++dd)
        *(float4*)(obase + (size_t)(d0 + dd) * rowstride) =
            make_float4(acc[dd][0], acc[dd][1], acc[dd][2], acc[dd][3]);
}

extern "C" void kernel_launch(void* const* d_in, const int* in_sizes, int n_in,
                              void* d_out, int out_size, void* d_ws, size_t ws_size,
                              hipStream_t stream) {
    const float* ref = (const float*)d_in[0];
    const float* tgt = (const float*)d_in[1];
    float* out = (float*)d_out;
    const int grid = NB * NG * HH;   // 2048 blocks, one per (b, g, h)
    gwc_kernel<<<dim3(grid), dim3(TPB), 0, stream>>>(ref, tgt, out);
}

// Round 8
// 76.518 us; speedup vs baseline: 6.5267x; 1.1884x over previous
//
#include <hip/hip_runtime.h>

// Problem: out[bg,d,h,w] = sum_c ref[bg,c,h,w]*tgt[bg,c,h,w-d]
// B*G=16, Cg=64, H=128, W=256, D=48. MFMA band-GEMM formulation.
#define NBG 16
#define HH 128
#define WW 256
#define CGR 64
#define ND 48
#define TPB 256
#define PITCH 40           // bf16 per LDS row: 32 data + 8 pad (16B-aligned rows)
#define OPITCH 132         // f32 out-buffer pitch (128 + 4)

typedef __attribute__((ext_vector_type(8))) short short8v;   // 8 bf16 = 4 VGPR
typedef __attribute__((ext_vector_type(4))) float float4v;   // MFMA C/D

__device__ __forceinline__ short f2bf(float x) {             // RNE f32->bf16
    unsigned u = __builtin_bit_cast(unsigned, x);
    u += 0x7fffu + ((u >> 16) & 1u);
    return (short)(u >> 16);
}

__global__ __launch_bounds__(TPB, 4)
void gwc_mfma(const float* __restrict__ ref, const float* __restrict__ tgt,
              float* __restrict__ out) {
    __shared__ __align__(16) short refT[128][PITCH];   // [w_local][c_local] bf16
    __shared__ __align__(16) short tgtT[176][PITCH];   // [w'_local][c_local], w' = W0-48+row
    __shared__ __align__(16) float outb[ND][OPITCH];   // [d][w_local]

    const int tid  = threadIdx.x;
    const int lane = tid & 63;
    const int wv   = tid >> 6;          // wave 0..3: n-tiles {wv, wv+4}
    const int fr   = lane & 15;         // frag row/col index
    const int fhi  = lane >> 4;         // frag k-group / C-row group

    const int blk  = blockIdx.x;        // ((bg*128 + h)*2 + half)
    const int half = blk & 1;
    const int h    = (blk >> 1) & (HH - 1);
    const int bg   = blk >> 8;
    const int W0   = half * 128;

    const size_t cstride = (size_t)HH * WW;   // 32768 floats between channels
    const float* refbase = ref + ((size_t)bg * CGR * HH + h) * WW;
    const float* tgtbase = tgt + ((size_t)bg * CGR * HH + h) * WW;

    float4v acc[2][4];
    #pragma unroll
    for (int j = 0; j < 2; ++j)
        #pragma unroll
        for (int i = 0; i < 4; ++i)
            acc[j][i] = (float4v){0.f, 0.f, 0.f, 0.f};

    for (int ch = 0; ch < 2; ++ch) {          // K-chunks of 32 channels
        if (ch) __syncthreads();              // prev chunk's frag reads done
        const int c0 = ch * 32;
        // ---- stage 304 w-columns: global (strided c, coalesced w) -> bf16 LDS ----
        #pragma unroll
        for (int rr = 0; rr < 2; ++rr) {
            const int row = tid + rr * 256;
            if (row < 304) {
                const bool isref = row < 128;
                const int  r  = isref ? row : row - 128;
                const int  wg = isref ? (W0 + r) : (W0 - 48 + r);
                short* dst = isref ? &refT[r][0] : &tgtT[r][0];
                if (wg >= 0) {
                    const float* p = (isref ? refbase : tgtbase) + (size_t)c0 * cstride + wg;
                    float v[32];
                    #pragma unroll
                    for (int cc = 0; cc < 32; ++cc) v[cc] = p[(size_t)cc * cstride];
                    #pragma unroll
                    for (int gq = 0; gq < 8; ++gq)
                        *(short4*)(dst + 4 * gq) =
                            make_short4(f2bf(v[4*gq]), f2bf(v[4*gq+1]),
                                        f2bf(v[4*gq+2]), f2bf(v[4*gq+3]));
                } else {  // left-image halo: zeros (reference zero-pad)
                    #pragma unroll
                    for (int gq = 0; gq < 8; ++gq)
                        *(short4*)(dst + 4 * gq) = make_short4(0, 0, 0, 0);
                }
            }
        }
        __syncthreads();
        // ---- band MFMAs: D[m=w'][n=w]; A=tgtT (row=fr, k=8*fhi+j), B=refT (col=fr) ----
        const short8v bfr0 = *(const short8v*)&refT[16 * wv + fr][8 * fhi];
        const short8v bfr1 = *(const short8v*)&refT[16 * (wv + 4) + fr][8 * fhi];
        #pragma unroll
        for (int j = 0; j < 2; ++j) {
            #pragma unroll
            for (int i = 0; i < 4; ++i) {
                const int mt = wv + 4 * j + i;   // m-tile (w'-dir), rows 16mt..16mt+15
                const short8v afr = *(const short8v*)&tgtT[16 * mt + fr][8 * fhi];
                acc[j][i] = __builtin_amdgcn_mfma_f32_16x16x32_bf16(
                    afr, (j ? bfr1 : bfr0), acc[j][i], 0, 0, 0);
            }
        }
    }

    // ---- scatter C frags into [d][w] LDS buffer (every cell written exactly once) ----
    #pragma unroll
    for (int j = 0; j < 2; ++j) {
        const int wl = 16 * (wv + 4 * j) + fr;          // n = col = fr
        #pragma unroll
        for (int i = 0; i < 4; ++i)
            #pragma unroll
            for (int rg = 0; rg < 4; ++rg) {
                const int d = 48 - 16 * i + fr - 4 * fhi - rg;   // w - w'
                if ((unsigned)d < (unsigned)ND)
                    outb[d][wl] = acc[j][i][rg];
            }
    }
    __syncthreads();
    // ---- coalesced store: out[((bg*48+d)*128+h)*256 + W0 + 4*wq] ----
    for (int s = tid; s < ND * 32; s += TPB) {
        const int dd = s >> 5;
        const int wq = s & 31;
        const float4 v = *(const float4*)&outb[dd][4 * wq];
        *(float4*)(out + ((size_t)(bg * ND + dd) * HH + h) * WW + W0 + 4 * wq) = v;
    }
}

extern "C" void kernel_launch(void* const* d_in, const int* in_sizes, int n_in,
                              void* d_out, int out_size, void* d_ws, size_t ws_size,
                              hipStream_t stream) {
    const float* ref = (const float*)d_in[0];
    const float* tgt = (const float*)d_in[1];
    float* out = (float*)d_out;
    const int grid = NBG * HH * 2;   // 4096 blocks: (bg, h, W-half)
    gwc_mfma<<<dim3(grid), dim3(TPB), 0, stream>>>(ref, tgt, out);
}

// Round 9
// 76.243 us; speedup vs baseline: 6.5502x; 1.0036x over previous
//
#include <hip/hip_runtime.h>

// Problem: out[bg,d,h,w] = sum_c ref[bg,c,h,w]*tgt[bg,c,h,w-d]
// B*G=16, Cg=64, H=128, W=256, D=48. MFMA band-GEMM formulation.
#define NBG 16
#define HH 128
#define WW 256
#define CGR 64
#define ND 48
#define TPB 256
#define PITCH 40           // bf16 per LDS row: 32 data + 8 pad (16B-aligned rows)
#define OPITCH 132         // f32 out-buffer pitch (128 + 4)

typedef __attribute__((ext_vector_type(8))) short short8v;   // 8 bf16 = 4 VGPR
typedef __attribute__((ext_vector_type(4))) float float4v;   // MFMA C/D

__device__ __forceinline__ short f2bf(float x) {             // RNE f32->bf16
    unsigned u = __builtin_bit_cast(unsigned, x);
    u += 0x7fffu + ((u >> 16) & 1u);
    return (short)(u >> 16);
}

// Staging buffers and the output buffer are never live at the same time:
// union them so LDS/block = 25.4 KB -> 6 blocks/CU (was 49.7 KB -> 3).
union SMem {
    struct {
        short refT[128][PITCH];   // [w_local][c_local] bf16
        short tgtT[176][PITCH];   // [w'_local][c_local], w' = W0-48+row
    } s;
    float outb[ND][OPITCH];       // [d][w_local]
};

__global__ __launch_bounds__(TPB, 6)
void gwc_mfma(const float* __restrict__ ref, const float* __restrict__ tgt,
              float* __restrict__ out) {
    __shared__ __align__(16) SMem sm;

    const int tid  = threadIdx.x;
    const int lane = tid & 63;
    const int wv   = tid >> 6;          // wave 0..3: n-tiles {wv, wv+4}
    const int fr   = lane & 15;         // frag row/col index
    const int fhi  = lane >> 4;         // frag k-group / C-row group

    const int blk  = blockIdx.x;        // ((bg*128 + h)*2 + half)
    const int half = blk & 1;
    const int h    = (blk >> 1) & (HH - 1);
    const int bg   = blk >> 8;
    const int W0   = half * 128;

    const size_t cstride = (size_t)HH * WW;   // 32768 floats between channels
    const float* refbase = ref + ((size_t)bg * CGR * HH + h) * WW;
    const float* tgtbase = tgt + ((size_t)bg * CGR * HH + h) * WW;

    float4v acc[2][4];
    #pragma unroll
    for (int j = 0; j < 2; ++j)
        #pragma unroll
        for (int i = 0; i < 4; ++i)
            acc[j][i] = (float4v){0.f, 0.f, 0.f, 0.f};

    for (int ch = 0; ch < 2; ++ch) {          // K-chunks of 32 channels
        if (ch) __syncthreads();              // prev chunk's frag reads done
        const int c0 = ch * 32;
        // ---- stage 304 w-columns: global (strided c, coalesced w) -> bf16 LDS ----
        #pragma unroll
        for (int rr = 0; rr < 2; ++rr) {
            const int row = tid + rr * 256;
            if (row < 304) {
                const bool isref = row < 128;
                const int  r  = isref ? row : row - 128;
                const int  wg = isref ? (W0 + r) : (W0 - 48 + r);
                short* dst = isref ? &sm.s.refT[r][0] : &sm.s.tgtT[r][0];
                if (wg >= 0) {
                    const float* p = (isref ? refbase : tgtbase) + (size_t)c0 * cstride + wg;
                    float v[32];
                    #pragma unroll
                    for (int cc = 0; cc < 32; ++cc) v[cc] = p[(size_t)cc * cstride];
                    #pragma unroll
                    for (int gq = 0; gq < 8; ++gq)
                        *(short4*)(dst + 4 * gq) =
                            make_short4(f2bf(v[4*gq]), f2bf(v[4*gq+1]),
                                        f2bf(v[4*gq+2]), f2bf(v[4*gq+3]));
                } else {  // left-image halo: zeros (reference zero-pad)
                    #pragma unroll
                    for (int gq = 0; gq < 8; ++gq)
                        *(short4*)(dst + 4 * gq) = make_short4(0, 0, 0, 0);
                }
            }
        }
        __syncthreads();
        // ---- band MFMAs: D[m=w'][n=w]; A=tgtT (row=fr, k=8*fhi+j), B=refT (col=fr) ----
        const short8v bfr0 = *(const short8v*)&sm.s.refT[16 * wv + fr][8 * fhi];
        const short8v bfr1 = *(const short8v*)&sm.s.refT[16 * (wv + 4) + fr][8 * fhi];
        #pragma unroll
        for (int j = 0; j < 2; ++j) {
            #pragma unroll
            for (int i = 0; i < 4; ++i) {
                const int mt = wv + 4 * j + i;   // m-tile (w'-dir), rows 16mt..16mt+15
                const short8v afr = *(const short8v*)&sm.s.tgtT[16 * mt + fr][8 * fhi];
                acc[j][i] = __builtin_amdgcn_mfma_f32_16x16x32_bf16(
                    afr, (j ? bfr1 : bfr0), acc[j][i], 0, 0, 0);
            }
        }
    }

    // union WAR hazard: all waves must finish MFMA reads before outb overwrites
    __syncthreads();
    // ---- scatter C frags into [d][w] LDS buffer (every cell written exactly once) ----
    #pragma unroll
    for (int j = 0; j < 2; ++j) {
        const int wl = 16 * (wv + 4 * j) + fr;          // n = col = fr
        #pragma unroll
        for (int i = 0; i < 4; ++i)
            #pragma unroll
            for (int rg = 0; rg < 4; ++rg) {
                const int d = 48 - 16 * i + fr - 4 * fhi - rg;   // w - w'
                if ((unsigned)d < (unsigned)ND)
                    sm.outb[d][wl] = acc[j][i][rg];
            }
    }
    __syncthreads();
    // ---- coalesced store: out[((bg*48+d)*128+h)*256 + W0 + 4*wq] ----
    for (int s = tid; s < ND * 32; s += TPB) {
        const int dd = s >> 5;
        const int wq = s & 31;
        const float4 v = *(const float4*)&sm.outb[dd][4 * wq];
        *(float4*)(out + ((size_t)(bg * ND + dd) * HH + h) * WW + W0 + 4 * wq) = v;
    }
}

extern "C" void kernel_launch(void* const* d_in, const int* in_sizes, int n_in,
                              void* d_out, int out_size, void* d_ws, size_t ws_size,
                              hipStream_t stream) {
    const float* ref = (const float*)d_in[0];
    const float* tgt = (const float*)d_in[1];
    float* out = (float*)d_out;
    const int grid = NBG * HH * 2;   // 4096 blocks: (bg, h, W-half)
    gwc_mfma<<<dim3(grid), dim3(TPB), 0, stream>>>(ref, tgt, out);
}